// Round 1
// 301.810 us; speedup vs baseline: 1.0501x; 1.0501x over previous
//
#include <hip/hip_runtime.h>

#define NEG_SLOPE 0.01f

constexpr int N_NODES_C = 50000;
constexpr int N_EDGES_C = 800000;
constexpr int M_PAD = 50048;  // 391 * 128

typedef short bf16x8 __attribute__((ext_vector_type(8)));
typedef float f32x4 __attribute__((ext_vector_type(4)));

__device__ inline unsigned short f2bf(float f) {
  unsigned int u = __float_as_uint(f);
  u += 0x7FFF + ((u >> 16) & 1);  // round-to-nearest-even
  return (unsigned short)(u >> 16);
}
__device__ inline float bf2f(unsigned int h16) {
  return __uint_as_float(h16 << 16);
}

// ---------------- fused preprocessing ----------------
constexpr int NB_CONVX = (M_PAD * 32) / 256;          // 6256
constexpr int NB_W1 = (256 * 256) / 256;              // 256
constexpr int NB_W2 = (256 * 128) / 256;              // 128
// histogram: 4 edges/thread, int4 loads (800000 % 4 == 0 -> no partial groups)
constexpr int NB_HIST = ((N_EDGES_C / 4) + 255) / 256;  // 782
constexpr int NB_PRE = NB_CONVX + NB_W1 + NB_W2 + NB_HIST;

__global__ __launch_bounds__(256) void pre_kernel(
    const float* __restrict__ x, const float* __restrict__ w1,
    const float* __restrict__ w2, const int* __restrict__ dst,
    unsigned short* __restrict__ xb, unsigned short* __restrict__ w1T,
    unsigned short* __restrict__ w2T, int* __restrict__ counts) {
  const int bx = blockIdx.x;
  const int tid = threadIdx.x;
  if (bx < NB_CONVX) {
    int idx = bx * 256 + tid;
    int row = idx >> 5;
    int c8 = (idx & 31) << 3;
    uint4 v;
    if (row < N_NODES_C) {
      const float4* p = (const float4*)(x + (size_t)row * 256 + c8);
      float4 a = p[0], b = p[1];
      v.x = f2bf(a.x) | ((unsigned)f2bf(a.y) << 16);
      v.y = f2bf(a.z) | ((unsigned)f2bf(a.w) << 16);
      v.z = f2bf(b.x) | ((unsigned)f2bf(b.y) << 16);
      v.w = f2bf(b.z) | ((unsigned)f2bf(b.w) << 16);
    } else {
      v = make_uint4(0, 0, 0, 0);
    }
    *(uint4*)(xb + (size_t)row * 256 + c8) = v;
  } else if (bx < NB_CONVX + NB_W1) {
    int idx = (bx - NB_CONVX) * 256 + tid;  // over [N=256][K=256]
    int n = idx >> 8, k = idx & 255;
    w1T[idx] = f2bf(w1[(size_t)k * 256 + n]);
  } else if (bx < NB_CONVX + NB_W1 + NB_W2) {
    int idx = (bx - NB_CONVX - NB_W1) * 256 + tid;  // over [N=128][K=256]
    int n = idx >> 8, k = idx & 255;
    w2T[idx] = f2bf(w2[(size_t)k * 128 + n]);
  } else {
    // 4-edge ILP histogram: independent atomics, vectorized index load
    int g = (bx - NB_CONVX - NB_W1 - NB_W2) * 256 + tid;
    int e = g * 4;
    if (e < N_EDGES_C) {
      int4 d4 = *(const int4*)(dst + e);
      atomicAdd(&counts[d4.x], 1);
      atomicAdd(&counts[d4.y], 1);
      atomicAdd(&counts[d4.z], 1);
      atomicAdd(&counts[d4.w], 1);
    }
  }
}

// ---------------- hierarchical scan (2 launches) ----------------
constexpr int N_SCAN_BLKS = (N_NODES_C + 255) / 256;  // 196

__global__ __launch_bounds__(256) void scan_phase_a(const int* __restrict__ counts,
                                                    int* __restrict__ partial,
                                                    int* __restrict__ blk_sums) {
  __shared__ int s[256];
  const int t = threadIdx.x;
  const int i = blockIdx.x * 256 + t;
  const int v = (i < N_NODES_C) ? counts[i] : 0;
  s[t] = v;
  __syncthreads();
  for (int off = 1; off < 256; off <<= 1) {
    int u = (t >= off) ? s[t - off] : 0;
    __syncthreads();
    s[t] += u;
    __syncthreads();
  }
  if (i < N_NODES_C) partial[i] = s[t] - v;
  if (t == 255) blk_sums[blockIdx.x] = s[255];
}

// each block redundantly scans the 196 block sums, then adds its own offset
__global__ __launch_bounds__(256) void scan_phase_bc(const int* __restrict__ partial,
                                                     const int* __restrict__ blk_sums,
                                                     int* __restrict__ row_ptr,
                                                     int* __restrict__ cursor) {
  __shared__ int s[256];
  __shared__ int blk_excl;
  const int t = threadIdx.x;
  const int v = (t < N_SCAN_BLKS) ? blk_sums[t] : 0;
  s[t] = v;
  __syncthreads();
  for (int off = 1; off < 256; off <<= 1) {
    int u = (t >= off) ? s[t - off] : 0;
    __syncthreads();
    s[t] += u;
    __syncthreads();
  }
  if (t == (int)blockIdx.x) blk_excl = s[t] - v;  // this block's exclusive offset
  __syncthreads();
  const int i = blockIdx.x * 256 + t;
  if (i < N_NODES_C) {
    const int r = partial[i] + blk_excl;
    row_ptr[i] = r;
    cursor[i] = r;
  }
  if (i == 0) row_ptr[N_NODES_C] = N_EDGES_C;
}

// ---------------- shared GEMM tile (device fn) ----------------
// C_sliced[slice][M_PAD][32] where slice = col/32

#define GLOAD_LDS16(g, l)                                              \
  __builtin_amdgcn_global_load_lds(                                    \
      (__attribute__((address_space(1))) void*)(g),                    \
      (__attribute__((address_space(3))) void*)(l), 16, 0, 0)

__device__ __forceinline__ void gemm_tile(
    const unsigned short* __restrict__ A,   // [M_PAD][256] bf16
    const unsigned short* __restrict__ BT,  // [N][256] bf16
    unsigned short* __restrict__ C,         // [N/32][M_PAD][32] sliced
    int N, int row0, int col0, short* Asm, short* Bsm) {
  constexpr int K = 256;
  const int tid = threadIdx.x;
  const int lane = tid & 63, wave = tid >> 6;
  const int wm = wave & 1, wn = wave >> 1;

  const int ch0 = wave * 2, ch1 = wave * 2 + 1;
  const int o0 = ch0 * 512 + lane * 8;
  const int o1 = ch1 * 512 + lane * 8;
  const int r0 = o0 >> 5, c0 = o0 & 31;
  const int r1 = o1 >> 5, c1 = o1 & 31;

  f32x4 acc[4][4] = {};

  for (int k0 = 0; k0 < K; k0 += 32) {
    GLOAD_LDS16(A + (size_t)(row0 + r0) * K + k0 + c0, &Asm[ch0 * 512]);
    GLOAD_LDS16(A + (size_t)(row0 + r1) * K + k0 + c1, &Asm[ch1 * 512]);
    GLOAD_LDS16(BT + (size_t)(col0 + r0) * K + k0 + c0, &Bsm[ch0 * 512]);
    GLOAD_LDS16(BT + (size_t)(col0 + r1) * K + k0 + c1, &Bsm[ch1 * 512]);
    __builtin_amdgcn_s_waitcnt(0);
    __syncthreads();

    bf16x8 af[4], bf[4];
#pragma unroll
    for (int mt = 0; mt < 4; ++mt)
      af[mt] = *(const bf16x8*)&Asm[(wm * 64 + mt * 16 + (lane & 15)) * 32 + (lane >> 4) * 8];
#pragma unroll
    for (int nt = 0; nt < 4; ++nt)
      bf[nt] = *(const bf16x8*)&Bsm[(wn * 64 + nt * 16 + (lane & 15)) * 32 + (lane >> 4) * 8];
#pragma unroll
    for (int mt = 0; mt < 4; ++mt)
#pragma unroll
      for (int nt = 0; nt < 4; ++nt)
        acc[mt][nt] = __builtin_amdgcn_mfma_f32_16x16x32_bf16(af[mt], bf[nt], acc[mt][nt], 0, 0, 0);
    __syncthreads();
  }

  const int cl = lane & 15, rq = (lane >> 4) * 4;
#pragma unroll
  for (int mt = 0; mt < 4; ++mt) {
    const int rbase = row0 + wm * 64 + mt * 16 + rq;
#pragma unroll
    for (int nt = 0; nt < 4; ++nt) {
      const int col = col0 + wn * 64 + nt * 16 + cl;
      const size_t sbase = ((size_t)(col >> 5) * M_PAD) * 32 + (col & 31);
#pragma unroll
      for (int i = 0; i < 4; ++i)
        C[sbase + (size_t)(rbase + i) * 32] = f2bf(acc[mt][nt][i]);
    }
  }
}

// ---------------- fused fill + gemm1 ----------------
// Even blocks: gemm1 tiles; odd blocks: CSR bucket fill (4 edges/thread).
// Interleaving keeps every CU holding a mix of compute-bound (gemm) and
// latency-bound (fill) blocks so MFMA hides the scatter latency.
// meta packed 4B: src(u16) | bf16(ew)<<16
constexpr int NB_GEMM1 = 2 * (M_PAD / 128);              // 782
constexpr int NB_FILL = ((N_EDGES_C / 4) + 255) / 256;   // 782 (== NB_GEMM1)

__global__ __launch_bounds__(256) void fill_gemm1_kernel(
    const unsigned short* __restrict__ A, const unsigned short* __restrict__ BT,
    unsigned short* __restrict__ C, const int* __restrict__ src,
    const int* __restrict__ dst, const float* __restrict__ ew,
    int* __restrict__ cursor, unsigned* __restrict__ s_meta) {
  __shared__ short Asm[128 * 32];
  __shared__ short Bsm[128 * 32];
  const int b = blockIdx.x;
  if ((b & 1) == 0) {
    const int t = b >> 1;  // [0, NB_GEMM1)
    gemm_tile(A, BT, C, 256, (t >> 1) * 128, (t & 1) * 128, Asm, Bsm);
  } else {
    const int g = (b >> 1) * 256 + threadIdx.x;  // 4-edge group id
    const int e = g * 4;
    if (e < N_EDGES_C) {
      int4 d4 = *(const int4*)(dst + e);
      int4 s4 = *(const int4*)(src + e);
      float4 w4 = *(const float4*)(ew + e);
      // pack meta before atomics so stores issue as soon as positions return
      unsigned m0 = (unsigned)s4.x | ((unsigned)f2bf(w4.x) << 16);
      unsigned m1 = (unsigned)s4.y | ((unsigned)f2bf(w4.y) << 16);
      unsigned m2 = (unsigned)s4.z | ((unsigned)f2bf(w4.z) << 16);
      unsigned m3 = (unsigned)s4.w | ((unsigned)f2bf(w4.w) << 16);
      int p0 = atomicAdd(&cursor[d4.x], 1);
      int p1 = atomicAdd(&cursor[d4.y], 1);
      int p2 = atomicAdd(&cursor[d4.z], 1);
      int p3 = atomicAdd(&cursor[d4.w], 1);
      // nontemporal: skip local-XCD L2 dirty lines (no RFO, no partial-line
      // writeback amplification across 8 non-coherent L2s)
      __builtin_nontemporal_store(m0, s_meta + p0);
      __builtin_nontemporal_store(m1, s_meta + p1);
      __builtin_nontemporal_store(m2, s_meta + p2);
      __builtin_nontemporal_store(m3, s_meta + p3);
    }
  }
}

__global__ __launch_bounds__(256) void gemm2_kernel(
    const unsigned short* __restrict__ A, const unsigned short* __restrict__ BT,
    unsigned short* __restrict__ C) {
  __shared__ short Asm[128 * 32];
  __shared__ short Bsm[128 * 32];
  gemm_tile(A, BT, C, 128, blockIdx.x * 128, 0, Asm, Bsm);
}

// ---------------- lite sliced aggregation ----------------
// ONE WAVE per block (64 thr) = 16 quad-nodes; slice = bx & (NSLICE-1) with
// slice-innermost ordering (tiny uniform blocks -> round-robin XCD pinning,
// narrow concurrent meta window -> table slice stays L2-resident; R6 evidence).
// 4 lanes per node; lane owns 8 dims; edges sequential; no reductions.

__device__ inline void fma8(float* acc, uint4 v, float wt) {
  acc[0] += bf2f(v.x & 0xffffu) * wt;
  acc[1] += bf2f(v.x >> 16) * wt;
  acc[2] += bf2f(v.y & 0xffffu) * wt;
  acc[3] += bf2f(v.y >> 16) * wt;
  acc[4] += bf2f(v.z & 0xffffu) * wt;
  acc[5] += bf2f(v.z >> 16) * wt;
  acc[6] += bf2f(v.w & 0xffffu) * wt;
  acc[7] += bf2f(v.w >> 16) * wt;
}

template <int NSLICE, int OUT_D, bool OUT_BF16>
__global__ __launch_bounds__(64) void agg_lite_kernel(
    const unsigned short* __restrict__ supS,  // [NSLICE][M_PAD][32]
    const unsigned* __restrict__ s_meta,      // src u16 | bf16(ew) << 16
    const int* __restrict__ row_ptr, const float* __restrict__ bias,
    unsigned short* __restrict__ out_bf, float* __restrict__ out_f, int n_total) {
  const int bx = blockIdx.x;
  const int slice = bx & (NSLICE - 1);
  const int group = bx / NSLICE;
  const int lane = threadIdx.x;  // 0..63
  const int quad = lane >> 2;    // node within group (0..15)
  const int dimg = lane & 3;     // 8-dim octet within 32-dim slice
  const int n = group * 16 + quad;
  if (n >= n_total) return;
  const bool valid = n < N_NODES_C;
  const unsigned short* tab = supS + (size_t)slice * M_PAD * 32;

  float acc[8] = {};
  if (valid) {
    int j = row_ptr[n];
    const int end = row_ptr[n + 1];
    for (; j + 2 <= end; j += 2) {
      unsigned m0 = s_meta[j];
      unsigned m1 = s_meta[j + 1];
      uint4 v0 = *(const uint4*)(tab + (m0 & 0xffffu) * 32 + dimg * 8);
      uint4 v1 = *(const uint4*)(tab + (m1 & 0xffffu) * 32 + dimg * 8);
      fma8(acc, v0, bf2f(m0 >> 16));
      fma8(acc, v1, bf2f(m1 >> 16));
    }
    if (j < end) {
      unsigned m0 = s_meta[j];
      uint4 v0 = *(const uint4*)(tab + (m0 & 0xffffu) * 32 + dimg * 8);
      fma8(acc, v0, bf2f(m0 >> 16));
    }
  }

  const int dbase = slice * 32 + dimg * 8;
  if (OUT_BF16) {
    unsigned short o[8];
#pragma unroll
    for (int j = 0; j < 8; ++j) {
      if (valid) {
        float v = acc[j] + bias[dbase + j];
        v = v >= 0.f ? v : NEG_SLOPE * v;
        o[j] = f2bf(v);
      } else {
        o[j] = 0;
      }
    }
    uint4 pk;
    pk.x = o[0] | ((unsigned)o[1] << 16);
    pk.y = o[2] | ((unsigned)o[3] << 16);
    pk.z = o[4] | ((unsigned)o[5] << 16);
    pk.w = o[6] | ((unsigned)o[7] << 16);
    *(uint4*)(out_bf + (size_t)n * OUT_D + dbase) = pk;
  } else if (valid) {
    float r[8];
#pragma unroll
    for (int j = 0; j < 8; ++j) {
      float v = acc[j] + bias[dbase + j];
      r[j] = v >= 0.f ? v : NEG_SLOPE * v;
    }
    *(float4*)(out_f + (size_t)n * OUT_D + dbase) = make_float4(r[0], r[1], r[2], r[3]);
    *(float4*)(out_f + (size_t)n * OUT_D + dbase + 4) = make_float4(r[4], r[5], r[6], r[7]);
  }
}

// ---------------- launch ----------------

extern "C" void kernel_launch(void* const* d_in, const int* in_sizes, int n_in,
                              void* d_out, int out_size, void* d_ws, size_t ws_size,
                              hipStream_t stream) {
  const float* x  = (const float*)d_in[0];   // [50000,256]
  const float* w1 = (const float*)d_in[1];   // [256,256]
  const float* b1 = (const float*)d_in[2];   // [256]
  const float* w2 = (const float*)d_in[3];   // [256,128]
  const float* b2 = (const float*)d_in[4];   // [128]
  const int*   src = (const int*)d_in[5];    // [800000]
  const int*   dst = (const int*)d_in[6];    // [800000]
  const float* ew  = (const float*)d_in[7];  // [800000]
  float* out = (float*)d_out;                // [50000,128]

  unsigned short* xb   = (unsigned short*)d_ws;              // M_PAD*256
  unsigned short* a2b  = xb + (size_t)M_PAD * 256;           // M_PAD*256
  unsigned short* sup1 = a2b + (size_t)M_PAD * 256;          // 8 x [M_PAD][32]
  unsigned short* sup2 = sup1 + (size_t)M_PAD * 256;         // 4 x [M_PAD][32]
  unsigned short* w1T  = sup2 + (size_t)M_PAD * 128;         // 256*256
  unsigned short* w2T  = w1T + 256 * 256;                    // 128*256
  int* counts  = (int*)(w2T + 128 * 256);                    // 50000
  int* cursor  = counts + N_NODES_C;                         // 50000
  int* row_ptr = cursor + N_NODES_C;                         // 50001
  int* partial = row_ptr + (N_NODES_C + 1);                  // 50000
  int* blk_sums= partial + N_NODES_C;                        // 256
  unsigned* s_meta = (unsigned*)(blk_sums + 256);            // 800000 * 4B

  // preprocessing: zero counts, then fused {conv_x, w1T, w2T, histogram}
  hipMemsetAsync(counts, 0, N_NODES_C * sizeof(int), stream);
  pre_kernel<<<NB_PRE, 256, 0, stream>>>(x, w1, w2, dst, xb, w1T, w2T, counts);

  // CSR scan
  scan_phase_a<<<N_SCAN_BLKS, 256, 0, stream>>>(counts, partial, blk_sums);
  scan_phase_bc<<<N_SCAN_BLKS, 256, 0, stream>>>(partial, blk_sums, row_ptr, cursor);

  // fused: CSR bucket fill + gemm1 (interleaved block types, one dispatch)
  fill_gemm1_kernel<<<NB_GEMM1 + NB_FILL, 256, 0, stream>>>(
      xb, w1T, sup1, src, dst, ew, cursor, s_meta);

  // layer-1 aggregation -> a2b (bf16, lrelu+bias fused)
  agg_lite_kernel<8, 256, true><<<(M_PAD / 16) * 8, 64, 0, stream>>>(
      sup1, s_meta, row_ptr, b1, a2b, nullptr, M_PAD);

  // layer 2
  gemm2_kernel<<<M_PAD / 128, 256, 0, stream>>>(a2b, w2T, sup2);
  agg_lite_kernel<4, 128, false><<<(N_NODES_C / 16) * 4, 64, 0, stream>>>(
      sup2, s_meta, row_ptr, b2, nullptr, out, N_NODES_C);
}